// Round 4
// baseline (332.922 us; speedup 1.0000x reference)
//
#include <hip/hip_runtime.h>

#define BB 2048
#define NN 200
#define DD 128
#define HH 8

typedef float f4v __attribute__((ext_vector_type(4)));

// ---------------------------------------------------------------------------
// Kernel 1: v[b][d] = sum_h Wr[h] * tanh( bq[d*8+h] + dot(q[b,:], Wq[d*8+h,:]) )
// Grid (4 j-chunks x 128 b-chunks), 256 threads. Thread owns one j = d*8+h,
// register-blocks 16 b's. Wq staged transposed in LDS (lane-consecutive reads),
// q read via wave-uniform scalar loads.  ~537 MFLOP total -> a few us.
// (unchanged from verified baseline)
// ---------------------------------------------------------------------------
__global__ __launch_bounds__(256) void proj_kernel(
    const float* __restrict__ q,    // (B, 128)
    const float* __restrict__ Wq,   // (1024, 128)
    const float* __restrict__ bq,   // (1024)
    const float* __restrict__ Wr,   // (1, 8)
    float* __restrict__ v)          // (B, 128)
{
    __shared__ float wq_s[32][257];           // [k within tile][j within chunk], padded
    const int t  = threadIdx.x;               // 0..255
    const int jc = blockIdx.x;                // 0..3   -> j chunk of 256
    const int b0 = blockIdx.y * 16;           // 0..2047 in steps of 16
    const int j  = jc * 256 + t;

    float acc[16];
#pragma unroll
    for (int i = 0; i < 16; ++i) acc[i] = 0.f;

    for (int kt = 0; kt < 4; ++kt) {          // k tiles of 32
        __syncthreads();
#pragma unroll
        for (int i = 0; i < 8; ++i) {
            int idx = t + 256 * i;            // 0..2047 f4 slots
            int jj  = idx >> 3;               // 0..255
            int kf  = idx & 7;                // 0..7
            const float4 w4 = *(const float4*)(Wq + (size_t)(jc*256 + jj)*128 + kt*32 + kf*4);
            wq_s[kf*4+0][jj] = w4.x;
            wq_s[kf*4+1][jj] = w4.y;
            wq_s[kf*4+2][jj] = w4.z;
            wq_s[kf*4+3][jj] = w4.w;
        }
        __syncthreads();

        float wreg[32];
#pragma unroll
        for (int k = 0; k < 32; ++k) wreg[k] = wq_s[k][t];   // lane-consecutive: conflict-free

#pragma unroll
        for (int bb = 0; bb < 16; ++bb) {
            const float* qrow = q + (size_t)(b0 + bb)*128 + kt*32;  // wave-uniform -> s_load
            float s = 0.f;
#pragma unroll
            for (int k = 0; k < 32; ++k) s = fmaf(qrow[k], wreg[k], s);
            acc[bb] += s;
        }
    }

    const float bqj = bq[j];
    const float wrh = Wr[j & 7];
    const int   d   = j >> 3;
#pragma unroll
    for (int bb = 0; bb < 16; ++bb) {
        float p = tanhf(acc[bb] + bqj) * wrh;
        p += __shfl_xor(p, 1);
        p += __shfl_xor(p, 2);
        p += __shfl_xor(p, 4);
        if ((t & 7) == 0) v[(size_t)(b0 + bb)*128 + d] = p;
    }
}

// ---------------------------------------------------------------------------
// Kernel 2: PERSISTENT blocks.  1024 blocks = 4 resident/CU x 256 CU (one
// residency round, zero block churn); each block owns 2 consecutive b's.
// 512 threads = 16 half-waves; half-wave owns rows {half + 16*i}; online
// softmax over N=200 in chunks {64,64,72}.
//
// Per-b math identical to the verified round-2 kernel: each half-wave keeps
// a PRIVATE flash state (m_h, l_h, o_h[4]) across chunks, rescaled lane-
// locally; the 16 states merge once per b in the epilogue.
//
// Cross-b pipelining: during b's LAST chunk we issue b+1's chunk-0 item
// loads, v-load, and mask staging -> the epilogue barrier + combine + store
// and the next-b startup all run UNDER in-flight HBM loads.  Epilogue LDS
// (mask_s / ml_s / stage) is parity-double-buffered so steady state needs
// exactly ONE barrier per b and the memory pipe never goes idle at a b
// boundary.
//
// LDS ~18.9 KB (4 blocks/CU fine); ~60 live VGPRs -> fits the 64-VGPR cap of
// __launch_bounds__(512, 8): 32 waves/CU.
// ---------------------------------------------------------------------------
__global__ __launch_bounds__(512, 8) void attn_kernel(
    const float* __restrict__ item,  // (B, 200, 128)
    const int*   __restrict__ mask,  // (B, 200) as int32
    const float* __restrict__ v,     // (B, 128)
    float* __restrict__ out)         // (B, 128)
{
    __shared__ float  mask_s[2][NN];                   // 0.0 / 1.0, per-b parity
    __shared__ float2 ml_s[2][16];                     // (m_h, l_h) per half
    __shared__ __align__(16) float stage[2][16][132];  // o combine, padded

    const int t    = threadIdx.x;      // 0..511
    const int seg  = t & 31;           // f4 segment within a row
    const int half = t >> 5;           // 0..15: half-wave id = row group
    const int b0   = blockIdx.x * 2;

    const float* itemb0 = item + (size_t)b0 * (NN * 128);
    const int*   maskb  = mask + (size_t)b0 * NN;
    const float* vb     = v + (size_t)b0 * 128;

    // stage mask for b0; prefetch b0 chunk 0; load v[b0]
    if (t < NN) mask_s[0][t] = maskb[t] ? 1.f : 0.f;

    f4v vreg = *(const f4v*)(vb + seg*4);
    f4v vnext = (f4v)0.f;

    f4v pre[5];
#pragma unroll
    for (int i = 0; i < 5; ++i) {
        const int row = half + 16*i;
        pre[i] = (f4v)0.f;
        if (row < 64)
            pre[i] = __builtin_nontemporal_load(
                (const f4v*)(itemb0 + (size_t)row*128 + seg*4));
    }
    __syncthreads();   // mask_s[0] visible

#pragma unroll
    for (int bi = 0; bi < 2; ++bi) {
        const float* itemb = itemb0 + (size_t)bi * (NN * 128);

        float mh = -3e38f, lh = 0.f;
        f4v oh = (f4v)0.f;

        for (int c = 0; c < 3; ++c) {
            const int base = c * 64;
            const int rows = (c == 2) ? 72 : 64;

            // ---- dot against v; 32-lane butterfly => all lanes hold pp[i] ----
            float pp[5];
#pragma unroll
            for (int i = 0; i < 5; ++i) {
                const f4v f = pre[i];
                float s = f[0]*vreg[0] + f[1]*vreg[1] + f[2]*vreg[2] + f[3]*vreg[3];
#pragma unroll
                for (int off = 16; off >= 1; off >>= 1)
                    s += __shfl_xor(s, off);
                pp[i] = s;
            }

            // ---- private running max over this half's valid rows (unmasked) ----
            float mn = mh;
#pragma unroll
            for (int i = 0; i < 5; ++i)
                if (half + 16*i < rows) mn = fmaxf(mn, pp[i]);

            const float alpha = __expf(mh - mn);   // chunk 0: exp(-3e38-x) -> 0
            mh = mn;
            lh *= alpha;
            oh[0] *= alpha; oh[1] *= alpha; oh[2] *= alpha; oh[3] *= alpha;

            // ---- masked exp weights + lane-local weighted accumulate ----
#pragma unroll
            for (int i = 0; i < 5; ++i) {
                const int row = half + 16*i;
                if (row < rows) {
                    const float w = mask_s[bi][base + row] * __expf(pp[i] - mn);
                    lh += w;
                    oh[0] = fmaf(w, pre[i][0], oh[0]);
                    oh[1] = fmaf(w, pre[i][1], oh[1]);
                    oh[2] = fmaf(w, pre[i][2], oh[2]);
                    oh[3] = fmaf(w, pre[i][3], oh[3]);
                }
            }

            // ---- pre[] dead: issue the NEXT stream's loads.
            //      c<2           -> next chunk of this b
            //      c==2 && bi==0 -> chunk 0 of b+1 (+ v[b+1] + mask staging)
            //      -> loads stay in flight across the epilogue barrier ----
            const bool pf = (c < 2) || (bi == 0);
            if (pf) {
                const int    nbase = (c < 2) ? (c + 1) * 64 : 0;
                const int    nrows = (c == 1) ? 72 : 64;
                const float* nptr  = (c < 2) ? itemb : itemb0 + (size_t)(NN * 128);
#pragma unroll
                for (int i = 0; i < 5; ++i) {
                    const int row = half + 16*i;
                    pre[i] = (f4v)0.f;
                    if (row < nrows)
                        pre[i] = __builtin_nontemporal_load(
                            (const f4v*)(nptr + (size_t)(nbase + row)*128 + seg*4));
                }
            }
            if (bi == 0 && c == 2) {
                vnext = *(const f4v*)(vb + 128 + seg*4);
                if (t < NN) mask_s[1][t] = maskb[NN + t] ? 1.f : 0.f;
            }
        }

        // ---- merge the 16 private flash states, once per b ----
        if (seg == 0) ml_s[bi][half] = make_float2(mh, lh);
        *(f4v*)(&stage[bi][half][seg*4]) = oh;   // lane-consecutive f4: conflict-free
        __syncthreads();   // also publishes mask_s[1] for the next b

        if (t < 128) {
            float mg = -3e38f;
#pragma unroll
            for (int h = 0; h < 16; ++h) mg = fmaxf(mg, ml_s[bi][h].x);
            float lsum = 0.f, tot = 0.f;
#pragma unroll
            for (int h = 0; h < 16; ++h) {
                const float sc = __expf(ml_s[bi][h].x - mg);
                lsum += ml_s[bi][h].y * sc;
                tot  = fmaf(stage[bi][h][t], sc, tot);
            }
            const float denom = (lsum < 1e-7f) ? (lsum + 1.f) : lsum;
            out[(size_t)(b0 + bi) * 128 + t] = tot / denom;
        }

        vreg = vnext;
    }
}

// ---------------------------------------------------------------------------
extern "C" void kernel_launch(void* const* d_in, const int* in_sizes, int n_in,
                              void* d_out, int out_size, void* d_ws, size_t ws_size,
                              hipStream_t stream) {
    const float* item = (const float*)d_in[0];   // (2048, 200, 128)
    const float* q    = (const float*)d_in[1];   // (2048, 128)
    const int*   mask = (const int*)  d_in[2];   // (2048, 200, 1) bool -> int32
    const float* Wq   = (const float*)d_in[3];   // (1024, 128)
    const float* bq   = (const float*)d_in[4];   // (1024)
    const float* Wr   = (const float*)d_in[5];   // (1, 8)
    float* out = (float*)d_out;                  // (2048, 128)
    float* v   = (float*)d_ws;                   // scratch: 2048*128*4 = 1 MiB

    proj_kernel<<<dim3(4, 128), 256, 0, stream>>>(q, Wq, bq, Wr, v);
    attn_kernel<<<dim3(BB/2), 512, 0, stream>>>(item, mask, v, out);
}